// Round 4
// baseline (229.696 us; speedup 1.0000x reference)
//
#include <hip/hip_runtime.h>
#include <stdint.h>

// out[r][c] = Y[r][c];  out[r][x[j]] += dt^2 * (deno @ X)[r][j]
// M = N = K = 4096, S = 64, dt^2 = 1e-6. Y/X/deno/out FP32, x int32.

#define MDIM 4096
#define NDIM 4096
#define SDIM 64
#define KDIM 4096
#define KSPLIT 4   // K-split across blockIdx.y; block K-range = 1024

typedef __bf16 bf16x8 __attribute__((ext_vector_type(8)));
typedef float  f32x4  __attribute__((ext_vector_type(4)));
union ABits { uint4 u; bf16x8 v; };

// ---------- 1. fused copy (out = Y) + transpose (XT[n][k] = bf16(X[k][n])) ----------
__global__ __launch_bounds__(256) void k_copy_tr(const float4* __restrict__ Y4,
                                                 float4* __restrict__ out4,
                                                 const float* __restrict__ X,
                                                 unsigned short* __restrict__ XT) {
    int g = blockIdx.x * 256 + threadIdx.x;          // 0 .. 2M-1
    out4[g]             = Y4[g];
    out4[g + (1 << 21)] = Y4[g + (1 << 21)];
    if (g < SDIM * KDIM) {                           // first 256K threads also transpose
        int n = g >> 12, k = g & (KDIM - 1);
        union { float f; unsigned u; } c; c.f = X[k * SDIM + n]; // strided, X=1MB L2
        XT[g] = (unsigned short)(c.u >> 16);         // truncate fp32 -> bf16
    }
}

// ---------- 2. GEMM (bf16 MFMA) + fused scatter atomicAdd into out ----------
// Grid (128, KSPLIT). Block = 512 thr (8 waves), m-tile 32 rows x 64 cols.
// Wave w handles K subrange of 128 (4 iters of 32). LDS reduce 8 waves, then
// 2048 atomicAdd(out[r][x[c]], dt^2 * s) per block (out already holds Y).
// mfma_f32_16x16x32_bf16 layouts (HW-verified, guide §3):
//   A[m][k]: m=lane&15, k=(lane>>4)*8+j ; B[k][n]: n=lane&15, k=(lane>>4)*8+j
//   D: col=lane&15, row=(lane>>4)*4+reg
__global__ __launch_bounds__(512, 4) void k_gemm_scatter(
    const float* __restrict__ deno, const unsigned short* __restrict__ XT,
    const int* __restrict__ x, float* __restrict__ out) {

    __shared__ float red[8][2048];   // per-wave partials: 32 rows x 64 cols

    const int t    = threadIdx.x;
    const int w    = t >> 6;
    const int lane = t & 63;
    const int r15  = lane & 15;
    const int q    = lane >> 4;
    const int m0   = blockIdx.x * 32;
    const int kw   = blockIdx.y * (KDIM / KSPLIT) + w * 128;

    const float* ap0 = deno + (size_t)(m0 + r15) * KDIM + kw + q * 8;
    const float* ap1 = ap0 + (size_t)16 * KDIM;
    const unsigned short* bp = XT + (size_t)r15 * KDIM + kw + q * 8;

    f32x4 acc[2][4] = {};

    for (int it = 0; it < 4; ++it) {
        uint4 a0lo = *(const uint4*)(ap0);
        uint4 a0hi = *(const uint4*)(ap0 + 4);
        uint4 a1lo = *(const uint4*)(ap1);
        uint4 a1hi = *(const uint4*)(ap1 + 4);
        bf16x8 b0 = *(const bf16x8*)(bp);
        bf16x8 b1 = *(const bf16x8*)(bp + 16 * (size_t)KDIM);
        bf16x8 b2 = *(const bf16x8*)(bp + 32 * (size_t)KDIM);
        bf16x8 b3 = *(const bf16x8*)(bp + 48 * (size_t)KDIM);

        ABits a0, a1;   // pack 8 fp32 -> 8 bf16 (truncation)
        a0.u.x = (a0lo.y & 0xFFFF0000u) | (a0lo.x >> 16);
        a0.u.y = (a0lo.w & 0xFFFF0000u) | (a0lo.z >> 16);
        a0.u.z = (a0hi.y & 0xFFFF0000u) | (a0hi.x >> 16);
        a0.u.w = (a0hi.w & 0xFFFF0000u) | (a0hi.z >> 16);
        a1.u.x = (a1lo.y & 0xFFFF0000u) | (a1lo.x >> 16);
        a1.u.y = (a1lo.w & 0xFFFF0000u) | (a1lo.z >> 16);
        a1.u.z = (a1hi.y & 0xFFFF0000u) | (a1hi.x >> 16);
        a1.u.w = (a1hi.w & 0xFFFF0000u) | (a1hi.z >> 16);

        acc[0][0] = __builtin_amdgcn_mfma_f32_16x16x32_bf16(a0.v, b0, acc[0][0], 0, 0, 0);
        acc[0][1] = __builtin_amdgcn_mfma_f32_16x16x32_bf16(a0.v, b1, acc[0][1], 0, 0, 0);
        acc[0][2] = __builtin_amdgcn_mfma_f32_16x16x32_bf16(a0.v, b2, acc[0][2], 0, 0, 0);
        acc[0][3] = __builtin_amdgcn_mfma_f32_16x16x32_bf16(a0.v, b3, acc[0][3], 0, 0, 0);
        acc[1][0] = __builtin_amdgcn_mfma_f32_16x16x32_bf16(a1.v, b0, acc[1][0], 0, 0, 0);
        acc[1][1] = __builtin_amdgcn_mfma_f32_16x16x32_bf16(a1.v, b1, acc[1][1], 0, 0, 0);
        acc[1][2] = __builtin_amdgcn_mfma_f32_16x16x32_bf16(a1.v, b2, acc[1][2], 0, 0, 0);
        acc[1][3] = __builtin_amdgcn_mfma_f32_16x16x32_bf16(a1.v, b3, acc[1][3], 0, 0, 0);

        ap0 += 32; ap1 += 32; bp += 32;
    }

    // per-wave partials -> LDS
#pragma unroll
    for (int mi = 0; mi < 2; ++mi)
#pragma unroll
        for (int ct = 0; ct < 4; ++ct)
#pragma unroll
            for (int reg = 0; reg < 4; ++reg)
                red[w][(mi * 16 + q * 4 + reg) * 64 + ct * 16 + r15] = acc[mi][ct][reg];
    __syncthreads();

    // reduce 8 waves + scatter-add into out (out already = Y)
#pragma unroll
    for (int i = 0; i < 4; ++i) {
        const int idx = t + 512 * i;         // 0..2047
        float s = 0.f;
#pragma unroll
        for (int ww = 0; ww < 8; ++ww) s += red[ww][idx];
        const int rl = idx >> 6;             // local row 0..31
        const int c  = idx & 63;             // src col 0..63
        atomicAdd(out + (size_t)(m0 + rl) * NDIM + x[c], 1e-6f * s);
    }
}

extern "C" void kernel_launch(void* const* d_in, const int* in_sizes, int n_in,
                              void* d_out, int out_size, void* d_ws, size_t ws_size,
                              hipStream_t stream) {
    const float* Y    = (const float*)d_in[0];
    const float* X    = (const float*)d_in[1];
    const float* deno = (const float*)d_in[2];
    const int*   x    = (const int*)d_in[3];

    unsigned short* XT = (unsigned short*)d_ws;    // 64*4096*2 B = 512 KB

    // 1) copy Y->out (2 float4/thread) + transpose X->XT
    k_copy_tr<<<(MDIM * NDIM) / 8 / 256, 256, 0, stream>>>(
        (const float4*)Y, (float4*)d_out, X, XT);

    // 2) src = deno @ X (bf16 MFMA), atomic scatter-add into out
    k_gemm_scatter<<<dim3(MDIM / 32, KSPLIT), 512, 0, stream>>>(
        deno, XT, x, (float*)d_out);
}

// Round 5
// 205.158 us; speedup vs baseline: 1.1196x; 1.1196x over previous
//
#include <hip/hip_runtime.h>
#include <stdint.h>

// out[r][c] = Y[r][c];  out[r][x[j]] += dt^2 * (deno @ X)[r][j]
// M = N = K = 4096, S = 64, dt^2 = 1e-6. Y/X/deno/out FP32, x int32.

#define MDIM 4096
#define NDIM 4096
#define SDIM 64
#define KDIM 4096
#define BM   16

typedef __bf16 bf16x8 __attribute__((ext_vector_type(8)));
typedef float  f32x4  __attribute__((ext_vector_type(4)));
union ABits { uint4 u; bf16x8 v; };

// ---------- 1. XT[n][k] = bf16(X[k][n]) ----------
__global__ __launch_bounds__(256) void k_transpose(const float* __restrict__ X,
                                                   unsigned short* __restrict__ XT) {
    int g = blockIdx.x * 256 + threadIdx.x;
    int n = g >> 12, k = g & (KDIM - 1);
    union { float f; unsigned u; } c; c.f = X[k * SDIM + n];
    XT[g] = (unsigned short)(c.u >> 16);
}

// ---------- 2. fused copy + GEMM + scatter ----------
// Block: 16 rows, 8 waves. Wave w: K-range [w*512,(w+1)*512), 16 iters of 32.
// Each iter also copies a linear 2KB chunk of Y->out (pure-BW filler traffic).
// Epilogue: LDS 8-way reduce, then plain stores to the 1024 scatter slots
// (rows are block-exclusive; lines are L2-dirty from our own copy).
// mfma_f32_16x16x32_bf16: A[m=lane&15][k=q*8+j], B[k=q*8+j][n=lane&15],
// D: col=lane&15, row=q*4+reg  (HW-verified, guide §3).
__global__ __launch_bounds__(512) void k_fused(
    const float* __restrict__ deno, const unsigned short* __restrict__ XT,
    const float* __restrict__ Y, const int* __restrict__ x,
    float* __restrict__ out) {

    __shared__ float red[8][BM * 64];   // 32 KB

    const int t    = threadIdx.x;
    const int w    = t >> 6;
    const int lane = t & 63;
    const int r15  = lane & 15;
    const int q    = lane >> 4;
    const int m0   = blockIdx.x * BM;
    const int kw   = w * (KDIM / 8);

    const float*          ap = deno + (size_t)(m0 + r15) * KDIM + kw + q * 8;
    const unsigned short* bp = XT + (size_t)r15 * KDIM + kw + q * 8;

    f32x4 acc0 = {0.f,0.f,0.f,0.f}, acc1 = {0.f,0.f,0.f,0.f};
    f32x4 acc2 = {0.f,0.f,0.f,0.f}, acc3 = {0.f,0.f,0.f,0.f};

#pragma unroll 2
    for (int it = 0; it < 16; ++it) {
        // --- linear copy chunk: 512 floats (rows m0+2w .. m0+2w+1) ---
        const int c = w * 16 + it;                       // 0..127, unique per block
        const size_t cb = (size_t)(m0 + (c >> 3)) * NDIM + (c & 7) * 512 + lane * 8;
        float4 y0 = *(const float4*)(Y + cb);
        float4 y1 = *(const float4*)(Y + cb + 4);

        // --- A: 8 fp32 (strided rows) ---
        uint4 alo = *(const uint4*)(ap);
        uint4 ahi = *(const uint4*)(ap + 4);

        // --- B: 4 x 16B from XT (L2-resident) ---
        bf16x8 b0 = *(const bf16x8*)(bp);
        bf16x8 b1 = *(const bf16x8*)(bp + 16 * (size_t)KDIM);
        bf16x8 b2 = *(const bf16x8*)(bp + 32 * (size_t)KDIM);
        bf16x8 b3 = *(const bf16x8*)(bp + 48 * (size_t)KDIM);

        *(float4*)(out + cb)     = y0;
        *(float4*)(out + cb + 4) = y1;

        ABits a;                      // pack 8 fp32 -> 8 bf16 (truncate)
        a.u.x = (alo.y & 0xFFFF0000u) | (alo.x >> 16);
        a.u.y = (alo.w & 0xFFFF0000u) | (alo.z >> 16);
        a.u.z = (ahi.y & 0xFFFF0000u) | (ahi.x >> 16);
        a.u.w = (ahi.w & 0xFFFF0000u) | (ahi.z >> 16);

        acc0 = __builtin_amdgcn_mfma_f32_16x16x32_bf16(a.v, b0, acc0, 0, 0, 0);
        acc1 = __builtin_amdgcn_mfma_f32_16x16x32_bf16(a.v, b1, acc1, 0, 0, 0);
        acc2 = __builtin_amdgcn_mfma_f32_16x16x32_bf16(a.v, b2, acc2, 0, 0, 0);
        acc3 = __builtin_amdgcn_mfma_f32_16x16x32_bf16(a.v, b3, acc3, 0, 0, 0);

        ap += 32; bp += 32;
    }

    // --- per-wave partials -> LDS ---
#pragma unroll
    for (int reg = 0; reg < 4; ++reg) {
        const int rl = q * 4 + reg;
        red[w][rl * 64 +  0 + r15] = acc0[reg];
        red[w][rl * 64 + 16 + r15] = acc1[reg];
        red[w][rl * 64 + 32 + r15] = acc2[reg];
        red[w][rl * 64 + 48 + r15] = acc3[reg];
    }
    __syncthreads();   // drains our copy stores too (vmcnt(0) before s_barrier)

    // --- reduce 8 waves + overwrite the 1024 scatter slots (non-atomic) ---
#pragma unroll
    for (int i = 0; i < 2; ++i) {
        const int idx = t + 512 * i;          // 0..1023
        float s = 0.f;
#pragma unroll
        for (int ww = 0; ww < 8; ++ww) s += red[ww][idx];
        const int rl = idx >> 6;              // local row 0..15
        const int cc = idx & 63;              // src col 0..63
        const size_t a = (size_t)(m0 + rl) * NDIM + x[cc];
        out[a] = Y[a] + 1e-6f * s;            // dt^2 = 1e-6; line is L2-hot
    }
}

extern "C" void kernel_launch(void* const* d_in, const int* in_sizes, int n_in,
                              void* d_out, int out_size, void* d_ws, size_t ws_size,
                              hipStream_t stream) {
    const float* Y    = (const float*)d_in[0];
    const float* X    = (const float*)d_in[1];
    const float* deno = (const float*)d_in[2];
    const int*   x    = (const int*)d_in[3];

    unsigned short* XT = (unsigned short*)d_ws;    // 512 KB

    k_transpose<<<(SDIM * KDIM) / 256, 256, 0, stream>>>(X, XT);
    k_fused<<<MDIM / BM, 512, 0, stream>>>(deno, XT, Y, x, (float*)d_out);
}